// Round 2
// baseline (748.853 us; speedup 1.0000x reference)
//
#include <hip/hip_runtime.h>
#include <cstdint>
#include <cstddef>

#define NN 8000
#define EE 64000
#define HH 10

// ---------------- ws layout (float offsets) ----------------
// deg      : 0          (NN)
// dout     : NN         (NN)      (init 1.0, accumulates outdeg -> outdeg+1)
// sum_in   : 2*NN       (64*NN)
// sum_src  : 66*NN      (64*NN)
// ea_sum   : 130*NN     (64*NN)
// eaQ      : 194*NN     (64*NN)   (= ea_sum @ Wek)
// eaK      : 258*NN     (64*NN)   (= ea_sum @ Weq)
// eaV      : 322*NN     (64*NN)   (= ea_sum @ Wev)
// xsrc     : 386*NN     (640*NN)
// NB       : 1026*NN    (640*NN)  (= node_update @ W4_bot)
// qk       : 1666*NN    (10*NN)
// sm       : 1676*NN    (10*NN)
// A        : 1686*NN    (64*EE)   (= edge_attr @ W4_top)
// total ~ 70.3 MB

__device__ __forceinline__ int rfl(int v) { return __builtin_amdgcn_readfirstlane(v); }

// ---------------------------------------------------------------------------
__global__ void k_init(float* __restrict__ ws, float* __restrict__ edge_out) {
  int t = blockIdx.x * 256 + threadIdx.x;
  int stride = gridDim.x * 256;
  for (int i = t; i < 130 * NN; i += stride)
    ws[i] = (i >= NN && i < 2 * NN) ? 1.0f : 0.0f;
  for (int i = t; i < EE * 64; i += stride)
    edge_out[i] = 0.0f;
}

// ---------------------------------------------------------------------------
__global__ void k_scatter(const int* __restrict__ ei, const float* __restrict__ ea,
                          float* __restrict__ deg, float* __restrict__ dout,
                          float* __restrict__ sum_in, float* __restrict__ sum_src) {
  int t = blockIdx.x * 256 + threadIdx.x;
  if (t >= EE * 64) return;
  int e = t >> 6, f = t & 63;
  int s = ei[e];
  int d = ei[EE + e];
  float v = ea[t];
  atomicAdd(&sum_in[d * 64 + f], v);
  atomicAdd(&sum_src[s * 64 + f], v);
  if (f == 0) {
    atomicAdd(&deg[d], 1.0f);
    atomicAdd(&dout[s], 1.0f);
  }
}

// ---------------------------------------------------------------------------
__global__ void k_easum(const float* __restrict__ deg, const float* __restrict__ sum_in,
                        const float* __restrict__ sum_src, float* __restrict__ ea_sum) {
  int t = blockIdx.x * 256 + threadIdx.x;
  if (t >= NN * 64) return;
  int n = t >> 6;
  ea_sum[t] = sum_src[t] + sum_in[t] / fmaxf(deg[n], 1.0f);
}

// ---------------------------------------------------------------------------
// Row template: out[r][c] = sum_f in[r][f] * W[f][c], weights-in-VGPR.
__global__ __launch_bounds__(256) void k_rowmm(const float* __restrict__ in,
                                               const float* __restrict__ W,
                                               float* __restrict__ out, int rows) {
  const int lane = threadIdx.x & 63;
  const int wv = rfl(threadIdx.x >> 6);
  float w[64];
#pragma unroll
  for (int f = 0; f < 64; ++f) w[f] = W[f * 64 + lane];
  const int nw = gridDim.x * 4;
  for (int r = blockIdx.x * 4 + wv; r < rows; r += nw) {
    const float* xr = in + (size_t)r * 64;
    float a0 = 0, a1 = 0, a2 = 0, a3 = 0;
#pragma unroll
    for (int f = 0; f < 64; f += 4) {
      a0 = fmaf(xr[f], w[f], a0);
      a1 = fmaf(xr[f + 1], w[f + 1], a1);
      a2 = fmaf(xr[f + 2], w[f + 2], a2);
      a3 = fmaf(xr[f + 3], w[f + 3], a3);
    }
    out[(size_t)r * 64 + lane] = (a0 + a1) + (a2 + a3);
  }
}

// ---------------------------------------------------------------------------
// xsrc[n, h*64+c] = sum_f x[n][f] * Wsrc[f][h*64+c]; gridDim.y = h
__global__ __launch_bounds__(256) void k_xsrc(const float* __restrict__ x,
                                              const float* __restrict__ Wsrc,
                                              float* __restrict__ xsrc) {
  const int h = blockIdx.y;
  const int lane = threadIdx.x & 63;
  const int wv = rfl(threadIdx.x >> 6);
  float w[64];
#pragma unroll
  for (int f = 0; f < 64; ++f) w[f] = Wsrc[f * 640 + h * 64 + lane];
  const int nw = gridDim.x * 4;
  for (int n = blockIdx.x * 4 + wv; n < NN; n += nw) {
    const float* xr = x + (size_t)n * 64;
    float a0 = 0, a1 = 0, a2 = 0, a3 = 0;
#pragma unroll
    for (int f = 0; f < 64; f += 4) {
      a0 = fmaf(xr[f], w[f], a0);
      a1 = fmaf(xr[f + 1], w[f + 1], a1);
      a2 = fmaf(xr[f + 2], w[f + 2], a2);
      a3 = fmaf(xr[f + 3], w[f + 3], a3);
    }
    xsrc[(size_t)n * 640 + h * 64 + lane] = (a0 + a1) + (a2 + a3);
  }
}

// ---------------------------------------------------------------------------
// eaQ = ea_sum@Wek, eaK = ea_sum@Weq, eaV = ea_sum@Wev   (naming per reference!)
__global__ __launch_bounds__(256) void k_eaqkv(const float* __restrict__ ea_sum,
                                               const float* __restrict__ Wek,
                                               const float* __restrict__ Weq,
                                               const float* __restrict__ Wev,
                                               float* __restrict__ eaQ,
                                               float* __restrict__ eaK,
                                               float* __restrict__ eaV) {
  const int lane = threadIdx.x & 63;
  const int wv = rfl(threadIdx.x >> 6);
  float wq[64], wk[64], wvv[64];
#pragma unroll
  for (int f = 0; f < 64; ++f) {
    wq[f] = Wek[f * 64 + lane];
    wk[f] = Weq[f * 64 + lane];
    wvv[f] = Wev[f * 64 + lane];
  }
  const int nw = gridDim.x * 4;
  for (int n = blockIdx.x * 4 + wv; n < NN; n += nw) {
    const float* r = ea_sum + (size_t)n * 64;
    float q0 = 0, q1 = 0, k0 = 0, k1 = 0, v0 = 0, v1 = 0;
#pragma unroll
    for (int f = 0; f < 64; f += 2) {
      q0 = fmaf(r[f], wq[f], q0);
      q1 = fmaf(r[f + 1], wq[f + 1], q1);
      k0 = fmaf(r[f], wk[f], k0);
      k1 = fmaf(r[f + 1], wk[f + 1], k1);
      v0 = fmaf(r[f], wvv[f], v0);
      v1 = fmaf(r[f + 1], wvv[f + 1], v1);
    }
    eaQ[(size_t)n * 64 + lane] = q0 + q1;
    eaK[(size_t)n * 64 + lane] = k0 + k1;
    eaV[(size_t)n * 64 + lane] = v0 + v1;
  }
}

// ---------------------------------------------------------------------------
// qk[n,h] = dot(Q_s, K_s)/8 ; Q_s = eaQ[n] + xsrc_row@Wnq ; K_s = dout*xsrc_row@Wnk + eaK[n]
__global__ __launch_bounds__(256) void k_qk(const float* __restrict__ xsrc,
                                            const float* __restrict__ Wnq,
                                            const float* __restrict__ Wnk,
                                            const float* __restrict__ eaQ,
                                            const float* __restrict__ eaK,
                                            const float* __restrict__ dout,
                                            float* __restrict__ qk) {
  const int lane = threadIdx.x & 63;
  const int wv = rfl(threadIdx.x >> 6);
  float wq[64], wk[64];
#pragma unroll
  for (int f = 0; f < 64; ++f) {
    wq[f] = Wnq[f * 64 + lane];
    wk[f] = Wnk[f * 64 + lane];
  }
  const int nw = gridDim.x * 4;
  for (int r = blockIdx.x * 4 + wv; r < NN * HH; r += nw) {
    int n = r / HH;
    const float* xr = xsrc + (size_t)r * 64;
    float q0 = 0, q1 = 0, k0 = 0, k1 = 0;
#pragma unroll
    for (int f = 0; f < 64; f += 2) {
      q0 = fmaf(xr[f], wq[f], q0);
      q1 = fmaf(xr[f + 1], wq[f + 1], q1);
      k0 = fmaf(xr[f], wk[f], k0);
      k1 = fmaf(xr[f + 1], wk[f + 1], k1);
    }
    float Q = (q0 + q1) + eaQ[(size_t)n * 64 + lane];
    float K = fmaf(dout[n], k0 + k1, eaK[(size_t)n * 64 + lane]);
    float p = Q * K;
#pragma unroll
    for (int off = 32; off; off >>= 1) p += __shfl_xor(p, off, 64);
    if (lane == 0) qk[r] = p * 0.125f;
  }
}

// ---------------------------------------------------------------------------
__global__ void k_softmax(const float* __restrict__ qk, float* __restrict__ sm) {
  int n = blockIdx.x * 256 + threadIdx.x;
  if (n >= NN) return;
  float v[HH];
  float mx = -1e30f;
#pragma unroll
  for (int h = 0; h < HH; ++h) {
    v[h] = qk[n * HH + h];
    mx = fmaxf(mx, v[h]);
  }
  float s = 0;
#pragma unroll
  for (int h = 0; h < HH; ++h) {
    v[h] = expf(v[h] - mx);
    s += v[h];
  }
  float inv = 1.0f / s;
#pragma unroll
  for (int h = 0; h < HH; ++h) sm[n * HH + h] = v[h] * inv;
}

// ---------------------------------------------------------------------------
// node_update + node_out + NB (= node_update @ W4_bot)
__global__ __launch_bounds__(256) void k_update(const float* __restrict__ xsrc,
                                                const float* __restrict__ Wnv,
                                                const float* __restrict__ W4,
                                                const float* __restrict__ eaV,
                                                const float* __restrict__ dout,
                                                const float* __restrict__ sm,
                                                const float* __restrict__ bias,
                                                float* __restrict__ node_out,
                                                float* __restrict__ NB) {
  __shared__ float lds[4][64];
  const int lane = threadIdx.x & 63;
  const int wv = rfl(threadIdx.x >> 6);
  float wvv[64], w4b[64];
#pragma unroll
  for (int f = 0; f < 64; ++f) {
    wvv[f] = Wnv[f * 64 + lane];
    w4b[f] = W4[(64 + f) * 64 + lane];
  }
  const int nw = gridDim.x * 4;
  for (int r = blockIdx.x * 4 + wv; r < NN * HH; r += nw) {
    int n = r / HH;
    int h = r - n * HH;
    const float* xr = xsrc + (size_t)r * 64;
    float a0 = 0, a1 = 0, a2 = 0, a3 = 0;
#pragma unroll
    for (int f = 0; f < 64; f += 4) {
      a0 = fmaf(xr[f], wvv[f], a0);
      a1 = fmaf(xr[f + 1], wvv[f + 1], a1);
      a2 = fmaf(xr[f + 2], wvv[f + 2], a2);
      a3 = fmaf(xr[f + 3], wvv[f + 3], a3);
    }
    float V = fmaf(dout[n], (a0 + a1) + (a2 + a3), eaV[(size_t)n * 64 + lane]);
    float nu = xr[lane] * sm[r] * V;
    node_out[(size_t)r * 64 + lane] = nu + bias[h * 64 + lane];
    lds[wv][lane] = nu;
    float b0 = 0, b1 = 0, b2 = 0, b3 = 0;
#pragma unroll
    for (int k = 0; k < 64; k += 4) {
      float4 m4 = *reinterpret_cast<const float4*>(&lds[wv][k]);
      b0 = fmaf(m4.x, w4b[k], b0);
      b1 = fmaf(m4.y, w4b[k + 1], b1);
      b2 = fmaf(m4.z, w4b[k + 2], b2);
      b3 = fmaf(m4.w, w4b[k + 3], b3);
    }
    NB[(size_t)r * 64 + lane] = (b0 + b1) + (b2 + b3);
  }
}

// ---------------------------------------------------------------------------
// Edge MLP: thread = (edge, head-group of 5). m=relu(A[e]+NB[src,h]);
// u=LN1(m@W5+ea); eu=LN2(u@W5+ea); edge_out[e] += eu*0.1 (mean over 10 heads).
__global__ __launch_bounds__(128, 2) void k_edge(const int* __restrict__ ei,
                                                 const float* __restrict__ ea_g,
                                                 const float* __restrict__ NB,
                                                 const float* __restrict__ A_ws,
                                                 const float* __restrict__ W5,
                                                 const float* __restrict__ g1,
                                                 const float* __restrict__ b1,
                                                 const float* __restrict__ g2,
                                                 const float* __restrict__ b2,
                                                 float* __restrict__ edge_out) {
  __shared__ float sU[128 * 65];
  const int tid = threadIdx.x;
  const int e = blockIdx.x * 128 + tid;
  const int hg = blockIdx.y;
  const int src = ei[e];
  const size_t e64 = (size_t)e * 64;

  float ea[64];
#pragma unroll
  for (int c = 0; c < 64; c += 4) {
    float4 v = *reinterpret_cast<const float4*>(ea_g + e64 + c);
    ea[c] = v.x; ea[c + 1] = v.y; ea[c + 2] = v.z; ea[c + 3] = v.w;
  }
  float acc[64];
#pragma unroll
  for (int c = 0; c < 64; ++c) acc[c] = 0.0f;

  const float* Arow = A_ws + e64;
  const float* NBbase = NB + (size_t)src * 640 + hg * (5 * 64);
  const int su = tid * 65;

  for (int h = 0; h < 5; ++h) {
    const float* nbr = NBbase + h * 64;
    // ---------------- matvec1: u = ea + W5^T relu(A + nb) ----------------
    float u[64];
#pragma unroll
    for (int c = 0; c < 64; ++c) u[c] = ea[c];
    float4 aC = *reinterpret_cast<const float4*>(Arow);
    float4 nC = *reinterpret_cast<const float4*>(nbr);
#pragma unroll 1
    for (int q = 0; q < 16; ++q) {
      const int qn = (q < 15) ? (q + 1) * 4 : 60;
      float4 aN = *reinterpret_cast<const float4*>(Arow + qn);
      float4 nN = *reinterpret_cast<const float4*>(nbr + qn);
      const float* wr = W5 + q * 256;
      float mf;
      mf = fmaxf(aC.x + nC.x, 0.0f);
#pragma unroll
      for (int c = 0; c < 64; ++c) u[c] = fmaf(mf, wr[c], u[c]);
      mf = fmaxf(aC.y + nC.y, 0.0f);
#pragma unroll
      for (int c = 0; c < 64; ++c) u[c] = fmaf(mf, wr[64 + c], u[c]);
      mf = fmaxf(aC.z + nC.z, 0.0f);
#pragma unroll
      for (int c = 0; c < 64; ++c) u[c] = fmaf(mf, wr[128 + c], u[c]);
      mf = fmaxf(aC.w + nC.w, 0.0f);
#pragma unroll
      for (int c = 0; c < 64; ++c) u[c] = fmaf(mf, wr[192 + c], u[c]);
      aC = aN; nC = nN;
    }
    // ---------------- LN1 ----------------
    {
      float s0 = 0, s1 = 0, t0 = 0, t1 = 0;
#pragma unroll
      for (int c = 0; c < 64; c += 2) {
        s0 += u[c];
        s1 += u[c + 1];
        t0 = fmaf(u[c], u[c], t0);
        t1 = fmaf(u[c + 1], u[c + 1], t1);
      }
      float mu = (s0 + s1) * 0.015625f;
      float var = (t0 + t1) * 0.015625f - mu * mu;
      float rs = rsqrtf(var);
#pragma unroll
      for (int c = 0; c < 64; ++c) {
        float t = (u[c] - mu) * rs * g1[c] + b1[c];
        sU[su + c] = t;
      }
    }
    // ---------------- matvec2: ep = ea + W5^T u ----------------
    float ep[64];
#pragma unroll
    for (int c = 0; c < 64; ++c) ep[c] = ea[c];
    float u0 = sU[su + 0], u1 = sU[su + 1], u2 = sU[su + 2], u3 = sU[su + 3];
#pragma unroll 1
    for (int q = 0; q < 16; ++q) {
      const int qn = (q < 15) ? (q + 1) * 4 : 60;
      float p0 = sU[su + qn], p1 = sU[su + qn + 1], p2 = sU[su + qn + 2], p3 = sU[su + qn + 3];
      const float* wr = W5 + q * 256;
#pragma unroll
      for (int c = 0; c < 64; ++c) ep[c] = fmaf(u0, wr[c], ep[c]);
#pragma unroll
      for (int c = 0; c < 64; ++c) ep[c] = fmaf(u1, wr[64 + c], ep[c]);
#pragma unroll
      for (int c = 0; c < 64; ++c) ep[c] = fmaf(u2, wr[128 + c], ep[c]);
#pragma unroll
      for (int c = 0; c < 64; ++c) ep[c] = fmaf(u3, wr[192 + c], ep[c]);
      u0 = p0; u1 = p1; u2 = p2; u3 = p3;
    }
    // ---------------- LN2 + accumulate ----------------
    {
      float s0 = 0, s1 = 0, t0 = 0, t1 = 0;
#pragma unroll
      for (int c = 0; c < 64; c += 2) {
        s0 += ep[c];
        s1 += ep[c + 1];
        t0 = fmaf(ep[c], ep[c], t0);
        t1 = fmaf(ep[c + 1], ep[c + 1], t1);
      }
      float mu = (s0 + s1) * 0.015625f;
      float var = (t0 + t1) * 0.015625f - mu * mu;
      float rs = rsqrtf(var);
#pragma unroll
      for (int c = 0; c < 64; ++c) acc[c] += (ep[c] - mu) * rs * g2[c] + b2[c];
    }
  }

  float* eo = edge_out + e64;
#pragma unroll
  for (int c = 0; c < 64; ++c) atomicAdd(eo + c, acc[c] * 0.1f);
}

// ---------------------------------------------------------------------------
extern "C" void kernel_launch(void* const* d_in, const int* in_sizes, int n_in,
                              void* d_out, int out_size, void* d_ws, size_t ws_size,
                              hipStream_t stream) {
  const float* x = (const float*)d_in[0];
  const int* ei = (const int*)d_in[1];
  const float* edge_attr = (const float*)d_in[2];
  const float* W_src = (const float*)d_in[3];
  const float* Wnq = (const float*)d_in[4];
  const float* Wnk = (const float*)d_in[5];
  const float* Wnv = (const float*)d_in[6];
  const float* Weq = (const float*)d_in[7];
  const float* Wev = (const float*)d_in[8];
  const float* Wek = (const float*)d_in[9];
  const float* W4 = (const float*)d_in[10];
  const float* W5 = (const float*)d_in[11];
  const float* g1 = (const float*)d_in[12];
  const float* b1 = (const float*)d_in[13];
  const float* g2 = (const float*)d_in[14];
  const float* b2 = (const float*)d_in[15];
  const float* bias = (const float*)d_in[16];
  (void)in_sizes; (void)n_in; (void)out_size; (void)ws_size;

  float* ws = (float*)d_ws;
  float* deg = ws;
  float* dout = ws + NN;
  float* sum_in = ws + 2 * NN;
  float* sum_src = ws + 66 * NN;
  float* ea_sum = ws + 130 * NN;
  float* eaQ = ws + 194 * NN;
  float* eaK = ws + 258 * NN;
  float* eaV = ws + 322 * NN;
  float* xsrc = ws + 386 * NN;
  float* NB = ws + 1026 * NN;
  float* qk = ws + 1666 * NN;
  float* sm = ws + 1676 * NN;
  float* A = ws + 1686 * NN;

  float* node_out = (float*)d_out;
  float* edge_out = (float*)d_out + (size_t)NN * 640;

  k_init<<<2048, 256, 0, stream>>>(ws, edge_out);
  k_scatter<<<EE * 64 / 256, 256, 0, stream>>>(ei, edge_attr, deg, dout, sum_in, sum_src);
  k_easum<<<NN * 64 / 256, 256, 0, stream>>>(deg, sum_in, sum_src, ea_sum);
  k_rowmm<<<512, 256, 0, stream>>>(edge_attr, W4, A, EE);  // A = ea @ W4_top
  k_xsrc<<<dim3(256, 10), 256, 0, stream>>>(x, W_src, xsrc);
  k_eaqkv<<<128, 256, 0, stream>>>(ea_sum, Wek, Weq, Wev, eaQ, eaK, eaV);
  k_qk<<<512, 256, 0, stream>>>(xsrc, Wnq, Wnk, eaQ, eaK, dout, qk);
  k_softmax<<<(NN + 255) / 256, 256, 0, stream>>>(qk, sm);
  k_update<<<512, 256, 0, stream>>>(xsrc, Wnv, W4, eaV, dout, sm, bias, node_out, NB);
  k_edge<<<dim3(EE / 128, 2), 128, 0, stream>>>(ei, edge_attr, NB, A, W5, g1, b1, g2, b2,
                                                edge_out);
}

// Round 3
// 722.793 us; speedup vs baseline: 1.0361x; 1.0361x over previous
//
#include <hip/hip_runtime.h>
#include <cstdint>
#include <cstddef>

#define NN 8000
#define EE 64000
#define HH 10
#define EPB 32  // edges per k_edge2 block (block = EPB*HH = 320 threads)

// ---------------- ws layout (float offsets) ----------------
// deg      : 0          (NN)
// dout     : NN         (NN)      (init 1.0, accumulates outdeg -> outdeg+1)
// sum_in   : 2*NN       (64*NN)
// sum_src  : 66*NN      (64*NN)
// ea_sum   : 130*NN     (64*NN)
// eaQ      : 194*NN     (64*NN)   (= ea_sum @ Wek)
// eaK      : 258*NN     (64*NN)   (= ea_sum @ Weq)
// eaV      : 322*NN     (64*NN)   (= ea_sum @ Wev)
// xsrc     : 386*NN     (640*NN)
// NB       : 1026*NN    (640*NN)  (= node_update @ W4_bot)
// qk       : 1666*NN    (10*NN)
// sm       : 1676*NN    (10*NN)
// A        : 1686*NN    (64*EE)   (= edge_attr @ W4_top)
// W5g      : 1686*NN+64*EE        (4096)   (= diag(g1) @ W5)
// Cg       : +4096                (64)     (= g1^T @ W5)
// Cb       : +64                  (64)     (= b1^T @ W5)

__device__ __forceinline__ int rfl(int v) { return __builtin_amdgcn_readfirstlane(v); }

// ---------------------------------------------------------------------------
__global__ void k_init(float* __restrict__ ws) {
  int t = blockIdx.x * 256 + threadIdx.x;
  int stride = gridDim.x * 256;
  for (int i = t; i < 130 * NN; i += stride)
    ws[i] = (i >= NN && i < 2 * NN) ? 1.0f : 0.0f;
}

// ---------------------------------------------------------------------------
__global__ void k_scatter(const int* __restrict__ ei, const float* __restrict__ ea,
                          float* __restrict__ deg, float* __restrict__ dout,
                          float* __restrict__ sum_in, float* __restrict__ sum_src) {
  int t = blockIdx.x * 256 + threadIdx.x;
  if (t >= EE * 64) return;
  int e = t >> 6, f = t & 63;
  int s = ei[e];
  int d = ei[EE + e];
  float v = ea[t];
  atomicAdd(&sum_in[d * 64 + f], v);
  atomicAdd(&sum_src[s * 64 + f], v);
  if (f == 0) {
    atomicAdd(&deg[d], 1.0f);
    atomicAdd(&dout[s], 1.0f);
  }
}

// ---------------------------------------------------------------------------
__global__ void k_easum(const float* __restrict__ deg, const float* __restrict__ sum_in,
                        const float* __restrict__ sum_src, float* __restrict__ ea_sum) {
  int t = blockIdx.x * 256 + threadIdx.x;
  if (t >= NN * 64) return;
  int n = t >> 6;
  ea_sum[t] = sum_src[t] + sum_in[t] / fmaxf(deg[n], 1.0f);
}

// ---------------------------------------------------------------------------
// W5g[f][c] = g1[f]*W5[f][c]; Cg[c] = sum_f g1[f]W5[f][c]; Cb[c] = sum_f b1[f]W5[f][c]
__global__ void k_prep(const float* __restrict__ W5, const float* __restrict__ g1,
                       const float* __restrict__ b1, float* __restrict__ W5g,
                       float* __restrict__ Cg, float* __restrict__ Cb) {
  int c = threadIdx.x;  // 64 threads
  float cg = 0.f, cb = 0.f;
  for (int f = 0; f < 64; ++f) {
    float w = W5[f * 64 + c];
    float gf = g1[f], bf = b1[f];
    W5g[f * 64 + c] = gf * w;
    cg = fmaf(gf, w, cg);
    cb = fmaf(bf, w, cb);
  }
  Cg[c] = cg;
  Cb[c] = cb;
}

// ---------------------------------------------------------------------------
// Row template: out[r][c] = sum_f in[r][f] * W[f][c], weights-in-VGPR.
__global__ __launch_bounds__(256) void k_rowmm(const float* __restrict__ in,
                                               const float* __restrict__ W,
                                               float* __restrict__ out, int rows) {
  const int lane = threadIdx.x & 63;
  const int wv = rfl(threadIdx.x >> 6);
  float w[64];
#pragma unroll
  for (int f = 0; f < 64; ++f) w[f] = W[f * 64 + lane];
  const int nw = gridDim.x * 4;
  for (int r = blockIdx.x * 4 + wv; r < rows; r += nw) {
    const float* xr = in + (size_t)r * 64;
    float a0 = 0, a1 = 0, a2 = 0, a3 = 0;
#pragma unroll
    for (int f = 0; f < 64; f += 4) {
      a0 = fmaf(xr[f], w[f], a0);
      a1 = fmaf(xr[f + 1], w[f + 1], a1);
      a2 = fmaf(xr[f + 2], w[f + 2], a2);
      a3 = fmaf(xr[f + 3], w[f + 3], a3);
    }
    out[(size_t)r * 64 + lane] = (a0 + a1) + (a2 + a3);
  }
}

// ---------------------------------------------------------------------------
// xsrc[n, h*64+c] = sum_f x[n][f] * Wsrc[f][h*64+c]; gridDim.y = h
__global__ __launch_bounds__(256) void k_xsrc(const float* __restrict__ x,
                                              const float* __restrict__ Wsrc,
                                              float* __restrict__ xsrc) {
  const int h = blockIdx.y;
  const int lane = threadIdx.x & 63;
  const int wv = rfl(threadIdx.x >> 6);
  float w[64];
#pragma unroll
  for (int f = 0; f < 64; ++f) w[f] = Wsrc[f * 640 + h * 64 + lane];
  const int nw = gridDim.x * 4;
  for (int n = blockIdx.x * 4 + wv; n < NN; n += nw) {
    const float* xr = x + (size_t)n * 64;
    float a0 = 0, a1 = 0, a2 = 0, a3 = 0;
#pragma unroll
    for (int f = 0; f < 64; f += 4) {
      a0 = fmaf(xr[f], w[f], a0);
      a1 = fmaf(xr[f + 1], w[f + 1], a1);
      a2 = fmaf(xr[f + 2], w[f + 2], a2);
      a3 = fmaf(xr[f + 3], w[f + 3], a3);
    }
    xsrc[(size_t)n * 640 + h * 64 + lane] = (a0 + a1) + (a2 + a3);
  }
}

// ---------------------------------------------------------------------------
// eaQ = ea_sum@Wek, eaK = ea_sum@Weq, eaV = ea_sum@Wev   (naming per reference!)
__global__ __launch_bounds__(256) void k_eaqkv(const float* __restrict__ ea_sum,
                                               const float* __restrict__ Wek,
                                               const float* __restrict__ Weq,
                                               const float* __restrict__ Wev,
                                               float* __restrict__ eaQ,
                                               float* __restrict__ eaK,
                                               float* __restrict__ eaV) {
  const int lane = threadIdx.x & 63;
  const int wv = rfl(threadIdx.x >> 6);
  float wq[64], wk[64], wvv[64];
#pragma unroll
  for (int f = 0; f < 64; ++f) {
    wq[f] = Wek[f * 64 + lane];
    wk[f] = Weq[f * 64 + lane];
    wvv[f] = Wev[f * 64 + lane];
  }
  const int nw = gridDim.x * 4;
  for (int n = blockIdx.x * 4 + wv; n < NN; n += nw) {
    const float* r = ea_sum + (size_t)n * 64;
    float q0 = 0, q1 = 0, k0 = 0, k1 = 0, v0 = 0, v1 = 0;
#pragma unroll
    for (int f = 0; f < 64; f += 2) {
      q0 = fmaf(r[f], wq[f], q0);
      q1 = fmaf(r[f + 1], wq[f + 1], q1);
      k0 = fmaf(r[f], wk[f], k0);
      k1 = fmaf(r[f + 1], wk[f + 1], k1);
      v0 = fmaf(r[f], wvv[f], v0);
      v1 = fmaf(r[f + 1], wvv[f + 1], v1);
    }
    eaQ[(size_t)n * 64 + lane] = q0 + q1;
    eaK[(size_t)n * 64 + lane] = k0 + k1;
    eaV[(size_t)n * 64 + lane] = v0 + v1;
  }
}

// ---------------------------------------------------------------------------
// qk[n,h] = dot(Q_s, K_s)/8
__global__ __launch_bounds__(256) void k_qk(const float* __restrict__ xsrc,
                                            const float* __restrict__ Wnq,
                                            const float* __restrict__ Wnk,
                                            const float* __restrict__ eaQ,
                                            const float* __restrict__ eaK,
                                            const float* __restrict__ dout,
                                            float* __restrict__ qk) {
  const int lane = threadIdx.x & 63;
  const int wv = rfl(threadIdx.x >> 6);
  float wq[64], wk[64];
#pragma unroll
  for (int f = 0; f < 64; ++f) {
    wq[f] = Wnq[f * 64 + lane];
    wk[f] = Wnk[f * 64 + lane];
  }
  const int nw = gridDim.x * 4;
  for (int r = blockIdx.x * 4 + wv; r < NN * HH; r += nw) {
    int n = r / HH;
    const float* xr = xsrc + (size_t)r * 64;
    float q0 = 0, q1 = 0, k0 = 0, k1 = 0;
#pragma unroll
    for (int f = 0; f < 64; f += 2) {
      q0 = fmaf(xr[f], wq[f], q0);
      q1 = fmaf(xr[f + 1], wq[f + 1], q1);
      k0 = fmaf(xr[f], wk[f], k0);
      k1 = fmaf(xr[f + 1], wk[f + 1], k1);
    }
    float Q = (q0 + q1) + eaQ[(size_t)n * 64 + lane];
    float K = fmaf(dout[n], k0 + k1, eaK[(size_t)n * 64 + lane]);
    float p = Q * K;
#pragma unroll
    for (int off = 32; off; off >>= 1) p += __shfl_xor(p, off, 64);
    if (lane == 0) qk[r] = p * 0.125f;
  }
}

// ---------------------------------------------------------------------------
__global__ void k_softmax(const float* __restrict__ qk, float* __restrict__ sm) {
  int n = blockIdx.x * 256 + threadIdx.x;
  if (n >= NN) return;
  float v[HH];
  float mx = -1e30f;
#pragma unroll
  for (int h = 0; h < HH; ++h) {
    v[h] = qk[n * HH + h];
    mx = fmaxf(mx, v[h]);
  }
  float s = 0;
#pragma unroll
  for (int h = 0; h < HH; ++h) {
    v[h] = expf(v[h] - mx);
    s += v[h];
  }
  float inv = 1.0f / s;
#pragma unroll
  for (int h = 0; h < HH; ++h) sm[n * HH + h] = v[h] * inv;
}

// ---------------------------------------------------------------------------
// node_update + node_out + NB (= node_update @ W4_bot)
__global__ __launch_bounds__(256) void k_update(const float* __restrict__ xsrc,
                                                const float* __restrict__ Wnv,
                                                const float* __restrict__ W4,
                                                const float* __restrict__ eaV,
                                                const float* __restrict__ dout,
                                                const float* __restrict__ sm,
                                                const float* __restrict__ bias,
                                                float* __restrict__ node_out,
                                                float* __restrict__ NB) {
  __shared__ float lds[4][64];
  const int lane = threadIdx.x & 63;
  const int wv = rfl(threadIdx.x >> 6);
  float wvv[64], w4b[64];
#pragma unroll
  for (int f = 0; f < 64; ++f) {
    wvv[f] = Wnv[f * 64 + lane];
    w4b[f] = W4[(64 + f) * 64 + lane];
  }
  const int nw = gridDim.x * 4;
  for (int r = blockIdx.x * 4 + wv; r < NN * HH; r += nw) {
    int n = r / HH;
    int h = r - n * HH;
    const float* xr = xsrc + (size_t)r * 64;
    float a0 = 0, a1 = 0, a2 = 0, a3 = 0;
#pragma unroll
    for (int f = 0; f < 64; f += 4) {
      a0 = fmaf(xr[f], wvv[f], a0);
      a1 = fmaf(xr[f + 1], wvv[f + 1], a1);
      a2 = fmaf(xr[f + 2], wvv[f + 2], a2);
      a3 = fmaf(xr[f + 3], wvv[f + 3], a3);
    }
    float V = fmaf(dout[n], (a0 + a1) + (a2 + a3), eaV[(size_t)n * 64 + lane]);
    float nu = xr[lane] * sm[r] * V;
    node_out[(size_t)r * 64 + lane] = nu + bias[h * 64 + lane];
    lds[wv][lane] = nu;
    float b0 = 0, b1 = 0, b2 = 0, b3 = 0;
#pragma unroll
    for (int k = 0; k < 64; k += 4) {
      float4 m4 = *reinterpret_cast<const float4*>(&lds[wv][k]);
      b0 = fmaf(m4.x, w4b[k], b0);
      b1 = fmaf(m4.y, w4b[k + 1], b1);
      b2 = fmaf(m4.z, w4b[k + 2], b2);
      b3 = fmaf(m4.w, w4b[k + 3], b3);
    }
    NB[(size_t)r * 64 + lane] = (b0 + b1) + (b2 + b3);
  }
}

// ---------------------------------------------------------------------------
// Edge MLP v2: thread = (edge, head). block = 32 edges x 10 heads = 320.
// u = ea + W5^T relu(A + NB[src,h]);  LN1 folded:
// ep = ea + Cb + rs1*(u @ W5g) - mu1*rs1*Cg;  eu = LN2(ep)*g2+b2;
// per-edge mean over heads via LDS atomic reduce, then one coalesced store.
__global__ __launch_bounds__(320, 2) void k_edge2(const int* __restrict__ ei,
                                                  const float* __restrict__ ea_g,
                                                  const float* __restrict__ NB,
                                                  const float* __restrict__ A_ws,
                                                  const float* __restrict__ W5,
                                                  const float* __restrict__ W5g,
                                                  const float* __restrict__ Cg,
                                                  const float* __restrict__ Cb,
                                                  const float* __restrict__ g2,
                                                  const float* __restrict__ b2,
                                                  float* __restrict__ edge_out) {
  __shared__ float accs[EPB * 65];
  const int tid = threadIdx.x;
  const int el = tid & 31;   // edge within block
  const int h = tid >> 5;    // head 0..9
  const int e = blockIdx.x * EPB + el;

  for (int i = tid; i < EPB * 65; i += 320) accs[i] = 0.f;
  __syncthreads();

  const int src = ei[e];
  const float* Arow = A_ws + (size_t)e * 64;
  const float* nbr = NB + (size_t)src * 640 + h * 64;
  const float* ear = ea_g + (size_t)e * 64;

  // ---------------- matvec1: u[c] = ea[c] + sum_f relu(A[f]+nb[f])*W5[f][c]
  float u[64];
#pragma unroll
  for (int c = 0; c < 64; c += 4) {
    float4 v = *reinterpret_cast<const float4*>(ear + c);
    u[c] = v.x; u[c + 1] = v.y; u[c + 2] = v.z; u[c + 3] = v.w;
  }
  {
    float4 aC = *reinterpret_cast<const float4*>(Arow);
    float4 nC = *reinterpret_cast<const float4*>(nbr);
#pragma unroll 1
    for (int q = 0; q < 16; ++q) {
      const int qn = (q < 15) ? (q + 1) * 4 : 60;
      float4 aN = *reinterpret_cast<const float4*>(Arow + qn);
      float4 nN = *reinterpret_cast<const float4*>(nbr + qn);
      const float* wr = W5 + q * 256;
      float mf;
      mf = fmaxf(aC.x + nC.x, 0.f);
#pragma unroll
      for (int c = 0; c < 64; ++c) u[c] = fmaf(mf, wr[c], u[c]);
      mf = fmaxf(aC.y + nC.y, 0.f);
#pragma unroll
      for (int c = 0; c < 64; ++c) u[c] = fmaf(mf, wr[64 + c], u[c]);
      mf = fmaxf(aC.z + nC.z, 0.f);
#pragma unroll
      for (int c = 0; c < 64; ++c) u[c] = fmaf(mf, wr[128 + c], u[c]);
      mf = fmaxf(aC.w + nC.w, 0.f);
#pragma unroll
      for (int c = 0; c < 64; ++c) u[c] = fmaf(mf, wr[192 + c], u[c]);
      aC = aN; nC = nN;
    }
  }

  // ---------------- LN1 stats (biased var, eps=0)
  float mu1, rs1;
  {
    float s0 = 0, s1 = 0, s2 = 0, s3 = 0;
    float t0 = 0, t1 = 0, t2 = 0, t3 = 0;
#pragma unroll
    for (int c = 0; c < 64; c += 4) {
      s0 += u[c]; s1 += u[c + 1]; s2 += u[c + 2]; s3 += u[c + 3];
      t0 = fmaf(u[c], u[c], t0);
      t1 = fmaf(u[c + 1], u[c + 1], t1);
      t2 = fmaf(u[c + 2], u[c + 2], t2);
      t3 = fmaf(u[c + 3], u[c + 3], t3);
    }
    mu1 = ((s0 + s1) + (s2 + s3)) * 0.015625f;
    float msq = ((t0 + t1) + (t2 + t3)) * 0.015625f;
    rs1 = rsqrtf(msq - mu1 * mu1);
  }

  // ---------------- matvec2: ep[c] = sum_f u[f] * W5g[f][c]  (fully unrolled:
  // multipliers come straight from u registers, statically indexed)
  float ep[64];
#pragma unroll
  for (int c = 0; c < 64; ++c) ep[c] = 0.f;
#pragma unroll
  for (int q = 0; q < 16; ++q) {
    const float* wr = W5g + q * 256;
    const float m0 = u[4 * q], m1 = u[4 * q + 1], m2 = u[4 * q + 2], m3 = u[4 * q + 3];
#pragma unroll
    for (int c = 0; c < 64; ++c) ep[c] = fmaf(m0, wr[c], ep[c]);
#pragma unroll
    for (int c = 0; c < 64; ++c) ep[c] = fmaf(m1, wr[64 + c], ep[c]);
#pragma unroll
    for (int c = 0; c < 64; ++c) ep[c] = fmaf(m2, wr[128 + c], ep[c]);
#pragma unroll
    for (int c = 0; c < 64; ++c) ep[c] = fmaf(m3, wr[192 + c], ep[c]);
  }

  // ---------------- y = ea + Cb + rs1*ep - mu1*rs1*Cg   (in place)
  {
    const float a2 = -mu1 * rs1;
#pragma unroll
    for (int c = 0; c < 64; c += 4) {
      float4 e4 = *reinterpret_cast<const float4*>(ear + c);
      float4 cb4 = *reinterpret_cast<const float4*>(Cb + c);
      float4 cg4 = *reinterpret_cast<const float4*>(Cg + c);
      ep[c] = fmaf(rs1, ep[c], fmaf(a2, cg4.x, e4.x + cb4.x));
      ep[c + 1] = fmaf(rs1, ep[c + 1], fmaf(a2, cg4.y, e4.y + cb4.y));
      ep[c + 2] = fmaf(rs1, ep[c + 2], fmaf(a2, cg4.z, e4.z + cb4.z));
      ep[c + 3] = fmaf(rs1, ep[c + 3], fmaf(a2, cg4.w, e4.w + cb4.w));
    }
  }

  // ---------------- LN2 stats
  float mu2, rs2;
  {
    float s0 = 0, s1 = 0, s2 = 0, s3 = 0;
    float t0 = 0, t1 = 0, t2 = 0, t3 = 0;
#pragma unroll
    for (int c = 0; c < 64; c += 4) {
      s0 += ep[c]; s1 += ep[c + 1]; s2 += ep[c + 2]; s3 += ep[c + 3];
      t0 = fmaf(ep[c], ep[c], t0);
      t1 = fmaf(ep[c + 1], ep[c + 1], t1);
      t2 = fmaf(ep[c + 2], ep[c + 2], t2);
      t3 = fmaf(ep[c + 3], ep[c + 3], t3);
    }
    mu2 = ((s0 + s1) + (s2 + s3)) * 0.015625f;
    float msq = ((t0 + t1) + (t2 + t3)) * 0.015625f;
    rs2 = rsqrtf(msq - mu2 * mu2);
  }

  // ---------------- eu = (ep-mu2)*rs2*g2 + b2 ; reduce over heads in LDS
  {
    float* accp = accs + el * 65;
#pragma unroll
    for (int c = 0; c < 64; c += 4) {
      float4 g4 = *reinterpret_cast<const float4*>(g2 + c);
      float4 b4 = *reinterpret_cast<const float4*>(b2 + c);
      atomicAdd(accp + c, fmaf((ep[c] - mu2) * rs2, g4.x, b4.x));
      atomicAdd(accp + c + 1, fmaf((ep[c + 1] - mu2) * rs2, g4.y, b4.y));
      atomicAdd(accp + c + 2, fmaf((ep[c + 2] - mu2) * rs2, g4.z, b4.z));
      atomicAdd(accp + c + 3, fmaf((ep[c + 3] - mu2) * rs2, g4.w, b4.w));
    }
  }
  __syncthreads();

  float* eo = edge_out + (size_t)blockIdx.x * (EPB * 64);
  for (int i = tid; i < EPB * 64; i += 320)
    eo[i] = accs[(i >> 6) * 65 + (i & 63)] * 0.1f;
}

// ---------------------------------------------------------------------------
extern "C" void kernel_launch(void* const* d_in, const int* in_sizes, int n_in,
                              void* d_out, int out_size, void* d_ws, size_t ws_size,
                              hipStream_t stream) {
  const float* x = (const float*)d_in[0];
  const int* ei = (const int*)d_in[1];
  const float* edge_attr = (const float*)d_in[2];
  const float* W_src = (const float*)d_in[3];
  const float* Wnq = (const float*)d_in[4];
  const float* Wnk = (const float*)d_in[5];
  const float* Wnv = (const float*)d_in[6];
  const float* Weq = (const float*)d_in[7];
  const float* Wev = (const float*)d_in[8];
  const float* Wek = (const float*)d_in[9];
  const float* W4 = (const float*)d_in[10];
  const float* W5 = (const float*)d_in[11];
  const float* g1 = (const float*)d_in[12];
  const float* b1 = (const float*)d_in[13];
  const float* g2 = (const float*)d_in[14];
  const float* b2 = (const float*)d_in[15];
  const float* bias = (const float*)d_in[16];
  (void)in_sizes; (void)n_in; (void)out_size; (void)ws_size;

  float* ws = (float*)d_ws;
  float* deg = ws;
  float* dout = ws + NN;
  float* sum_in = ws + 2 * NN;
  float* sum_src = ws + 66 * NN;
  float* ea_sum = ws + 130 * NN;
  float* eaQ = ws + 194 * NN;
  float* eaK = ws + 258 * NN;
  float* eaV = ws + 322 * NN;
  float* xsrc = ws + 386 * NN;
  float* NB = ws + 1026 * NN;
  float* qk = ws + 1666 * NN;
  float* sm = ws + 1676 * NN;
  float* A = ws + 1686 * NN;
  float* W5g = ws + 1686 * NN + 64 * EE;
  float* Cg = W5g + 4096;
  float* Cb = Cg + 64;

  float* node_out = (float*)d_out;
  float* edge_out = (float*)d_out + (size_t)NN * 640;

  k_init<<<1024, 256, 0, stream>>>(ws);
  k_prep<<<1, 64, 0, stream>>>(W5, g1, b1, W5g, Cg, Cb);
  k_scatter<<<EE * 64 / 256, 256, 0, stream>>>(ei, edge_attr, deg, dout, sum_in, sum_src);
  k_easum<<<NN * 64 / 256, 256, 0, stream>>>(deg, sum_in, sum_src, ea_sum);
  k_rowmm<<<512, 256, 0, stream>>>(edge_attr, W4, A, EE);  // A = ea @ W4_top
  k_xsrc<<<dim3(256, 10), 256, 0, stream>>>(x, W_src, xsrc);
  k_eaqkv<<<128, 256, 0, stream>>>(ea_sum, Wek, Weq, Wev, eaQ, eaK, eaV);
  k_qk<<<512, 256, 0, stream>>>(xsrc, Wnq, Wnk, eaQ, eaK, dout, qk);
  k_softmax<<<(NN + 255) / 256, 256, 0, stream>>>(qk, sm);
  k_update<<<512, 256, 0, stream>>>(xsrc, Wnv, W4, eaV, dout, sm, bias, node_out, NB);
  k_edge2<<<EE / EPB, EPB * HH, 0, stream>>>(ei, edge_attr, NB, A, W5, W5g, Cg, Cb, g2, b2,
                                             edge_out);
}

// Round 4
// 548.076 us; speedup vs baseline: 1.3663x; 1.3188x over previous
//
#include <hip/hip_runtime.h>
#include <cstdint>
#include <cstddef>

#define NN 8000
#define EE 64000
#define HH 10
#define WPB 4  // waves (edges) per k_edge3 block

// ---------------- ws layout (float offsets) ----------------
// deg      : 0          (NN)
// dout     : NN         (NN)      (init 1.0, accumulates outdeg -> outdeg+1)
// sum_in   : 2*NN       (64*NN)
// sum_src  : 66*NN      (64*NN)
// ea_sum   : 130*NN     (64*NN)
// eaQ      : 194*NN     (64*NN)   (= ea_sum @ Wek)
// eaK      : 258*NN     (64*NN)   (= ea_sum @ Weq)
// eaV      : 322*NN     (64*NN)   (= ea_sum @ Wev)
// xsrc     : 386*NN     (640*NN)
// NB       : 1026*NN    (640*NN)  (= node_update @ W4_bot)
// qk       : 1666*NN    (10*NN)
// sm       : 1676*NN    (10*NN)
// A        : 1686*NN    (64*EE)   (= edge_attr @ W4_top)
// Cg       : 1686*NN+64*EE  (64)  (= g1^T @ W5)
// Cb       : +64            (64)  (= b1^T @ W5)

__device__ __forceinline__ int rfl(int v) { return __builtin_amdgcn_readfirstlane(v); }

// ---------------------------------------------------------------------------
__global__ void k_init(float* __restrict__ ws) {
  int t = blockIdx.x * 256 + threadIdx.x;
  int stride = gridDim.x * 256;
  for (int i = t; i < 130 * NN; i += stride)
    ws[i] = (i >= NN && i < 2 * NN) ? 1.0f : 0.0f;
}

// ---------------------------------------------------------------------------
__global__ void k_scatter(const int* __restrict__ ei, const float* __restrict__ ea,
                          float* __restrict__ deg, float* __restrict__ dout,
                          float* __restrict__ sum_in, float* __restrict__ sum_src) {
  int t = blockIdx.x * 256 + threadIdx.x;
  if (t >= EE * 64) return;
  int e = t >> 6, f = t & 63;
  int s = ei[e];
  int d = ei[EE + e];
  float v = ea[t];
  atomicAdd(&sum_in[d * 64 + f], v);
  atomicAdd(&sum_src[s * 64 + f], v);
  if (f == 0) {
    atomicAdd(&deg[d], 1.0f);
    atomicAdd(&dout[s], 1.0f);
  }
}

// ---------------------------------------------------------------------------
__global__ void k_easum(const float* __restrict__ deg, const float* __restrict__ sum_in,
                        const float* __restrict__ sum_src, float* __restrict__ ea_sum) {
  int t = blockIdx.x * 256 + threadIdx.x;
  if (t >= NN * 64) return;
  int n = t >> 6;
  ea_sum[t] = sum_src[t] + sum_in[t] / fmaxf(deg[n], 1.0f);
}

// ---------------------------------------------------------------------------
// Cg[c] = sum_f g1[f]W5[f][c]; Cb[c] = sum_f b1[f]W5[f][c]
__global__ void k_prep(const float* __restrict__ W5, const float* __restrict__ g1,
                       const float* __restrict__ b1, float* __restrict__ Cg,
                       float* __restrict__ Cb) {
  int c = threadIdx.x;  // 64 threads
  float cg = 0.f, cb = 0.f;
  for (int f = 0; f < 64; ++f) {
    float w = W5[f * 64 + c];
    cg = fmaf(g1[f], w, cg);
    cb = fmaf(b1[f], w, cb);
  }
  Cg[c] = cg;
  Cb[c] = cb;
}

// ---------------------------------------------------------------------------
// Row template: out[r][c] = sum_f in[r][f] * W[f][c], weights-in-VGPR.
__global__ __launch_bounds__(256) void k_rowmm(const float* __restrict__ in,
                                               const float* __restrict__ W,
                                               float* __restrict__ out, int rows) {
  const int lane = threadIdx.x & 63;
  const int wv = rfl(threadIdx.x >> 6);
  float w[64];
#pragma unroll
  for (int f = 0; f < 64; ++f) w[f] = W[f * 64 + lane];
  const int nw = gridDim.x * 4;
  for (int r = blockIdx.x * 4 + wv; r < rows; r += nw) {
    const float* xr = in + (size_t)r * 64;
    float a0 = 0, a1 = 0, a2 = 0, a3 = 0;
#pragma unroll
    for (int f = 0; f < 64; f += 4) {
      a0 = fmaf(xr[f], w[f], a0);
      a1 = fmaf(xr[f + 1], w[f + 1], a1);
      a2 = fmaf(xr[f + 2], w[f + 2], a2);
      a3 = fmaf(xr[f + 3], w[f + 3], a3);
    }
    out[(size_t)r * 64 + lane] = (a0 + a1) + (a2 + a3);
  }
}

// ---------------------------------------------------------------------------
// xsrc[n, h*64+c] = sum_f x[n][f] * Wsrc[f][h*64+c]; gridDim.y = h
__global__ __launch_bounds__(256) void k_xsrc(const float* __restrict__ x,
                                              const float* __restrict__ Wsrc,
                                              float* __restrict__ xsrc) {
  const int h = blockIdx.y;
  const int lane = threadIdx.x & 63;
  const int wv = rfl(threadIdx.x >> 6);
  float w[64];
#pragma unroll
  for (int f = 0; f < 64; ++f) w[f] = Wsrc[f * 640 + h * 64 + lane];
  const int nw = gridDim.x * 4;
  for (int n = blockIdx.x * 4 + wv; n < NN; n += nw) {
    const float* xr = x + (size_t)n * 64;
    float a0 = 0, a1 = 0, a2 = 0, a3 = 0;
#pragma unroll
    for (int f = 0; f < 64; f += 4) {
      a0 = fmaf(xr[f], w[f], a0);
      a1 = fmaf(xr[f + 1], w[f + 1], a1);
      a2 = fmaf(xr[f + 2], w[f + 2], a2);
      a3 = fmaf(xr[f + 3], w[f + 3], a3);
    }
    xsrc[(size_t)n * 640 + h * 64 + lane] = (a0 + a1) + (a2 + a3);
  }
}

// ---------------------------------------------------------------------------
// eaQ = ea_sum@Wek, eaK = ea_sum@Weq, eaV = ea_sum@Wev   (naming per reference!)
__global__ __launch_bounds__(256) void k_eaqkv(const float* __restrict__ ea_sum,
                                               const float* __restrict__ Wek,
                                               const float* __restrict__ Weq,
                                               const float* __restrict__ Wev,
                                               float* __restrict__ eaQ,
                                               float* __restrict__ eaK,
                                               float* __restrict__ eaV) {
  const int lane = threadIdx.x & 63;
  const int wv = rfl(threadIdx.x >> 6);
  float wq[64], wk[64], wvv[64];
#pragma unroll
  for (int f = 0; f < 64; ++f) {
    wq[f] = Wek[f * 64 + lane];
    wk[f] = Weq[f * 64 + lane];
    wvv[f] = Wev[f * 64 + lane];
  }
  const int nw = gridDim.x * 4;
  for (int n = blockIdx.x * 4 + wv; n < NN; n += nw) {
    const float* r = ea_sum + (size_t)n * 64;
    float q0 = 0, q1 = 0, k0 = 0, k1 = 0, v0 = 0, v1 = 0;
#pragma unroll
    for (int f = 0; f < 64; f += 2) {
      q0 = fmaf(r[f], wq[f], q0);
      q1 = fmaf(r[f + 1], wq[f + 1], q1);
      k0 = fmaf(r[f], wk[f], k0);
      k1 = fmaf(r[f + 1], wk[f + 1], k1);
      v0 = fmaf(r[f], wvv[f], v0);
      v1 = fmaf(r[f + 1], wvv[f + 1], v1);
    }
    eaQ[(size_t)n * 64 + lane] = q0 + q1;
    eaK[(size_t)n * 64 + lane] = k0 + k1;
    eaV[(size_t)n * 64 + lane] = v0 + v1;
  }
}

// ---------------------------------------------------------------------------
// qk[n,h] = dot(Q_s, K_s)/8
__global__ __launch_bounds__(256) void k_qk(const float* __restrict__ xsrc,
                                            const float* __restrict__ Wnq,
                                            const float* __restrict__ Wnk,
                                            const float* __restrict__ eaQ,
                                            const float* __restrict__ eaK,
                                            const float* __restrict__ dout,
                                            float* __restrict__ qk) {
  const int lane = threadIdx.x & 63;
  const int wv = rfl(threadIdx.x >> 6);
  float wq[64], wk[64];
#pragma unroll
  for (int f = 0; f < 64; ++f) {
    wq[f] = Wnq[f * 64 + lane];
    wk[f] = Wnk[f * 64 + lane];
  }
  const int nw = gridDim.x * 4;
  for (int r = blockIdx.x * 4 + wv; r < NN * HH; r += nw) {
    int n = r / HH;
    const float* xr = xsrc + (size_t)r * 64;
    float q0 = 0, q1 = 0, k0 = 0, k1 = 0;
#pragma unroll
    for (int f = 0; f < 64; f += 2) {
      q0 = fmaf(xr[f], wq[f], q0);
      q1 = fmaf(xr[f + 1], wq[f + 1], q1);
      k0 = fmaf(xr[f], wk[f], k0);
      k1 = fmaf(xr[f + 1], wk[f + 1], k1);
    }
    float Q = (q0 + q1) + eaQ[(size_t)n * 64 + lane];
    float K = fmaf(dout[n], k0 + k1, eaK[(size_t)n * 64 + lane]);
    float p = Q * K;
#pragma unroll
    for (int off = 32; off; off >>= 1) p += __shfl_xor(p, off, 64);
    if (lane == 0) qk[r] = p * 0.125f;
  }
}

// ---------------------------------------------------------------------------
__global__ void k_softmax(const float* __restrict__ qk, float* __restrict__ sm) {
  int n = blockIdx.x * 256 + threadIdx.x;
  if (n >= NN) return;
  float v[HH];
  float mx = -1e30f;
#pragma unroll
  for (int h = 0; h < HH; ++h) {
    v[h] = qk[n * HH + h];
    mx = fmaxf(mx, v[h]);
  }
  float s = 0;
#pragma unroll
  for (int h = 0; h < HH; ++h) {
    v[h] = expf(v[h] - mx);
    s += v[h];
  }
  float inv = 1.0f / s;
#pragma unroll
  for (int h = 0; h < HH; ++h) sm[n * HH + h] = v[h] * inv;
}

// ---------------------------------------------------------------------------
// node_update + node_out + NB (= node_update @ W4_bot)
__global__ __launch_bounds__(256) void k_update(const float* __restrict__ xsrc,
                                                const float* __restrict__ Wnv,
                                                const float* __restrict__ W4,
                                                const float* __restrict__ eaV,
                                                const float* __restrict__ dout,
                                                const float* __restrict__ sm,
                                                const float* __restrict__ bias,
                                                float* __restrict__ node_out,
                                                float* __restrict__ NB) {
  __shared__ float lds[4][64];
  const int lane = threadIdx.x & 63;
  const int wv = rfl(threadIdx.x >> 6);
  float wvv[64], w4b[64];
#pragma unroll
  for (int f = 0; f < 64; ++f) {
    wvv[f] = Wnv[f * 64 + lane];
    w4b[f] = W4[(64 + f) * 64 + lane];
  }
  const int nw = gridDim.x * 4;
  for (int r = blockIdx.x * 4 + wv; r < NN * HH; r += nw) {
    int n = r / HH;
    int h = r - n * HH;
    const float* xr = xsrc + (size_t)r * 64;
    float a0 = 0, a1 = 0, a2 = 0, a3 = 0;
#pragma unroll
    for (int f = 0; f < 64; f += 4) {
      a0 = fmaf(xr[f], wvv[f], a0);
      a1 = fmaf(xr[f + 1], wvv[f + 1], a1);
      a2 = fmaf(xr[f + 2], wvv[f + 2], a2);
      a3 = fmaf(xr[f + 3], wvv[f + 3], a3);
    }
    float V = fmaf(dout[n], (a0 + a1) + (a2 + a3), eaV[(size_t)n * 64 + lane]);
    float nu = xr[lane] * sm[r] * V;
    node_out[(size_t)r * 64 + lane] = nu + bias[h * 64 + lane];
    lds[wv][lane] = nu;
    float b0 = 0, b1 = 0, b2 = 0, b3 = 0;
#pragma unroll
    for (int k = 0; k < 64; k += 4) {
      float4 m4 = *reinterpret_cast<const float4*>(&lds[wv][k]);
      b0 = fmaf(m4.x, w4b[k], b0);
      b1 = fmaf(m4.y, w4b[k + 1], b1);
      b2 = fmaf(m4.z, w4b[k + 2], b2);
      b3 = fmaf(m4.w, w4b[k + 3], b3);
    }
    NB[(size_t)r * 64 + lane] = (b0 + b1) + (b2 + b3);
  }
}

// ---------------------------------------------------------------------------
// Edge MLP v3: WAVE per edge, lane = output channel c. Heads looped inside.
// Row-valued multipliers broadcast via per-wave LDS slot (uniform ds_read_b128).
// u_raw = ea + W5^T relu(A + NB[src,h])          (matvec1)
// LN1 folded: ep = ea + Cb + rs1*(W5^T (u_raw.*g1)) - mu1*rs1*Cg
// eu = LN2(ep)*g2 + b2 ; edge_out = mean_h eu
__global__ __launch_bounds__(256) void k_edge3(const int* __restrict__ ei,
                                               const float* __restrict__ ea_g,
                                               const float* __restrict__ NB,
                                               const float* __restrict__ A_ws,
                                               const float* __restrict__ W5,
                                               const float* __restrict__ Cg,
                                               const float* __restrict__ Cb,
                                               const float* __restrict__ g1v,
                                               const float* __restrict__ g2v,
                                               const float* __restrict__ b2v,
                                               float* __restrict__ edge_out) {
  __shared__ float bcast[WPB][64];  // one 256B broadcast slot per wave
  const int lane = threadIdx.x & 63;
  const int wv = rfl(threadIdx.x >> 6);
  // per-lane weight column W5[:, lane] + per-lane constants (loaded once)
  float w5[64];
#pragma unroll
  for (int f = 0; f < 64; ++f) w5[f] = W5[f * 64 + lane];
  const float cg_c = Cg[lane];
  const float cb_c = Cb[lane];
  const float g1_c = g1v[lane];
  const float g2_c = g2v[lane];
  const float b2_c = b2v[lane];

  const int e = blockIdx.x * WPB + wv;  // grid is exact: EE/WPB blocks
  const int src = ei[e];
  const float ea_c = ea_g[(size_t)e * 64 + lane];
  const float A_c = A_ws[(size_t)e * 64 + lane];
  const float* nbp = NB + (size_t)src * 640 + lane;
  float* bc = &bcast[wv][0];

  float acc = 0.f;
  float nbv = nbp[0];
#pragma unroll 1
  for (int h = 0; h < HH; ++h) {
    float nbn = (h < HH - 1) ? nbp[(h + 1) * 64] : 0.f;  // prefetch next head
    // ---- matvec1: broadcast m = relu(A+nb), accumulate u = ea + sum m_f*W5[f][c]
    float m = fmaxf(A_c + nbv, 0.f);
    bc[lane] = m;
    float u = ea_c;
#pragma unroll
    for (int q = 0; q < 16; ++q) {
      float4 mv = *reinterpret_cast<const float4*>(bc + 4 * q);  // uniform addr: broadcast
      u = fmaf(mv.x, w5[4 * q], u);
      u = fmaf(mv.y, w5[4 * q + 1], u);
      u = fmaf(mv.z, w5[4 * q + 2], u);
      u = fmaf(mv.w, w5[4 * q + 3], u);
    }
    // ---- LN1 stats across lanes (biased var, eps=0)
    float s = u, s2 = u * u;
#pragma unroll
    for (int off = 1; off < 64; off <<= 1) {
      s += __shfl_xor(s, off, 64);
      s2 += __shfl_xor(s2, off, 64);
    }
    float mu1 = s * 0.015625f;
    float rs1 = rsqrtf(s2 * 0.015625f - mu1 * mu1);
    // ---- matvec2: broadcast u*g1, accumulate ep = sum (u_f g1_f) * W5[f][c]
    bc[lane] = u * g1_c;
    float ep = 0.f;
#pragma unroll
    for (int q = 0; q < 16; ++q) {
      float4 mv = *reinterpret_cast<const float4*>(bc + 4 * q);
      ep = fmaf(mv.x, w5[4 * q], ep);
      ep = fmaf(mv.y, w5[4 * q + 1], ep);
      ep = fmaf(mv.z, w5[4 * q + 2], ep);
      ep = fmaf(mv.w, w5[4 * q + 3], ep);
    }
    float base = fmaf(-mu1 * rs1, cg_c, ea_c + cb_c);
    ep = fmaf(rs1, ep, base);
    // ---- LN2 stats
    float t = ep, t2 = ep * ep;
#pragma unroll
    for (int off = 1; off < 64; off <<= 1) {
      t += __shfl_xor(t, off, 64);
      t2 += __shfl_xor(t2, off, 64);
    }
    float mu2 = t * 0.015625f;
    float rs2 = rsqrtf(t2 * 0.015625f - mu2 * mu2);
    acc += fmaf((ep - mu2) * rs2, g2_c, b2_c);
    nbv = nbn;
  }
  edge_out[(size_t)e * 64 + lane] = acc * 0.1f;
}

// ---------------------------------------------------------------------------
extern "C" void kernel_launch(void* const* d_in, const int* in_sizes, int n_in,
                              void* d_out, int out_size, void* d_ws, size_t ws_size,
                              hipStream_t stream) {
  const float* x = (const float*)d_in[0];
  const int* ei = (const int*)d_in[1];
  const float* edge_attr = (const float*)d_in[2];
  const float* W_src = (const float*)d_in[3];
  const float* Wnq = (const float*)d_in[4];
  const float* Wnk = (const float*)d_in[5];
  const float* Wnv = (const float*)d_in[6];
  const float* Weq = (const float*)d_in[7];
  const float* Wev = (const float*)d_in[8];
  const float* Wek = (const float*)d_in[9];
  const float* W4 = (const float*)d_in[10];
  const float* W5 = (const float*)d_in[11];
  const float* g1 = (const float*)d_in[12];
  const float* b1 = (const float*)d_in[13];
  const float* g2 = (const float*)d_in[14];
  const float* b2 = (const float*)d_in[15];
  const float* bias = (const float*)d_in[16];
  (void)in_sizes; (void)n_in; (void)out_size; (void)ws_size;

  float* ws = (float*)d_ws;
  float* deg = ws;
  float* dout = ws + NN;
  float* sum_in = ws + 2 * NN;
  float* sum_src = ws + 66 * NN;
  float* ea_sum = ws + 130 * NN;
  float* eaQ = ws + 194 * NN;
  float* eaK = ws + 258 * NN;
  float* eaV = ws + 322 * NN;
  float* xsrc = ws + 386 * NN;
  float* NB = ws + 1026 * NN;
  float* qk = ws + 1666 * NN;
  float* sm = ws + 1676 * NN;
  float* A = ws + 1686 * NN;
  float* Cg = ws + 1686 * NN + 64 * EE;
  float* Cb = Cg + 64;

  float* node_out = (float*)d_out;
  float* edge_out = (float*)d_out + (size_t)NN * 640;

  k_init<<<1024, 256, 0, stream>>>(ws);
  k_prep<<<1, 64, 0, stream>>>(W5, g1, b1, Cg, Cb);
  k_scatter<<<EE * 64 / 256, 256, 0, stream>>>(ei, edge_attr, deg, dout, sum_in, sum_src);
  k_easum<<<NN * 64 / 256, 256, 0, stream>>>(deg, sum_in, sum_src, ea_sum);
  k_rowmm<<<512, 256, 0, stream>>>(edge_attr, W4, A, EE);  // A = ea @ W4_top
  k_xsrc<<<dim3(256, 10), 256, 0, stream>>>(x, W_src, xsrc);
  k_eaqkv<<<128, 256, 0, stream>>>(ea_sum, Wek, Weq, Wev, eaQ, eaK, eaV);
  k_qk<<<512, 256, 0, stream>>>(xsrc, Wnq, Wnk, eaQ, eaK, dout, qk);
  k_softmax<<<(NN + 255) / 256, 256, 0, stream>>>(qk, sm);
  k_update<<<512, 256, 0, stream>>>(xsrc, Wnv, W4, eaV, dout, sm, bias, node_out, NB);
  k_edge3<<<EE / WPB, WPB * 64, 0, stream>>>(ei, edge_attr, NB, A, W5, Cg, Cb, g1, g2, b2,
                                             edge_out);
}